// Round 3
// baseline (528.813 us; speedup 1.0000x reference)
//
#include <hip/hip_runtime.h>

#define BB 2
#define NN 2048
#define HH 16
#define MODEL 1024
#define CSC 0.18033688011112042f  // 0.125 * log2(e)

typedef short bf16x8 __attribute__((ext_vector_type(8)));
typedef float f32x4 __attribute__((ext_vector_type(4)));

__device__ __forceinline__ unsigned short f2bf(float x) {
  unsigned int u = __builtin_bit_cast(unsigned int, x);
  u += 0x7fffu + ((u >> 16) & 1u);
  return (unsigned short)(u >> 16);
}

__device__ __forceinline__ unsigned int pack_bf2(float a, float b) {
  unsigned int ua = __builtin_bit_cast(unsigned int, a) + 0x8000u;
  unsigned int ub = __builtin_bit_cast(unsigned int, b) + 0x8000u;
  return __builtin_amdgcn_perm(ub, ua, 0x07060302u);  // lo16=bf(a), hi16=bf(b)
}

__device__ __forceinline__ float fast_exp2(float x) {
#if __has_builtin(__builtin_amdgcn_exp2f)
  return __builtin_amdgcn_exp2f(x);
#else
  return exp2f(x);
#endif
}

__device__ __forceinline__ f32x4 mfma16(bf16x8 a, bf16x8 b, f32x4 c) {
  return __builtin_amdgcn_mfma_f32_16x16x32_bf16(a, b, c, 0, 0, 0);
}

__device__ __forceinline__ void async_copy16(void* lds_base, const void* g) {
  __builtin_amdgcn_global_load_lds(
      (const __attribute__((address_space(1))) void*)g,
      (__attribute__((address_space(3))) void*)lds_base, 16, 0, 0);
}

// fused bf16 conversion of q, k, w_out (one launch instead of three)
__global__ void cvt3_kernel(const float* __restrict__ q, const float* __restrict__ k,
                            const float* __restrict__ w, unsigned short* __restrict__ qb,
                            unsigned short* __restrict__ kb, unsigned short* __restrict__ wb) {
  const int NQ = BB * NN * MODEL / 4;  // 1048576 float4s
  const int NW = MODEL * MODEL / 4;    // 262144
  int i = blockIdx.x * 256 + threadIdx.x;
  const float* src;
  unsigned short* dst;
  int j = i;
  if (i < NQ) {
    src = q; dst = qb;
  } else if (i < 2 * NQ) {
    src = k; dst = kb; j = i - NQ;
  } else if (i < 2 * NQ + NW) {
    src = w; dst = wb; j = i - 2 * NQ;
  } else {
    return;
  }
  float4 f = reinterpret_cast<const float4*>(src)[j];
  ushort4 u;
  u.x = f2bf(f.x); u.y = f2bf(f.y); u.z = f2bf(f.z); u.w = f2bf(f.w);
  reinterpret_cast<ushort4*>(dst)[j] = u;
}

// vt[b][h][d][n] = bf16(v[b][n][h*64+d])
__global__ void transpose_v_kernel(const float* __restrict__ v,
                                   unsigned short* __restrict__ vt) {
  __shared__ unsigned short tile[64][65];
  int n0 = blockIdx.x * 64;
  int bh = blockIdx.y;
  int b = bh >> 4, h = bh & 15;
  int c = threadIdx.x & 63;
  int r = threadIdx.x >> 6;
#pragma unroll
  for (int i = 0; i < 16; ++i) {
    int nl = r * 16 + i;
    tile[c][nl] = f2bf(v[((long)(b * NN + n0 + nl)) * MODEL + h * 64 + c]);
  }
  __syncthreads();
#pragma unroll
  for (int i = 0; i < 16; ++i) {
    int d = r * 16 + i;
    vt[((long)(bh * 64 + d)) * NN + n0 + c] = tile[d][c];
  }
}

// biasTab[h][rel+2047] = bias(rel) * 0.125 * log2(e)  (log2-domain, pre-scaled)
__global__ void bias_table_kernel(const float* __restrict__ rel_emb,
                                  float* __restrict__ biasTab) {
  int idx = blockIdx.x * 256 + threadIdx.x;
  if (idx >= 4095) return;
  int rel = idx - 2047;
  int nn = rel < 0 ? -rel : rel;
  int bucket;
  if (nn < 8) {
    bucket = nn;
  } else {
    float val = logf((float)nn * 0.125f) / logf(16.0f) * 8.0f;
    int vl = 8 + (int)val;
    if (vl > 15) vl = 15;
    bucket = vl;
  }
  if (rel >= 0) bucket += 16;
#pragma unroll
  for (int h = 0; h < 16; ++h)
    biasTab[h * 4095 + idx] = rel_emb[bucket * 16 + h] * CSC;
}

// Flash attention v3: kt-split waves, S^T, direct-to-reg K/V, b64 P-writes,
// two-phase O merge (LDS 38.9 KB -> 4 blocks/CU).
__global__ __launch_bounds__(256, 4) void flash3(
    const unsigned short* __restrict__ qb, const unsigned short* __restrict__ kb,
    const unsigned short* __restrict__ vtb, const float* __restrict__ biasTab,
    unsigned short* __restrict__ attn) {
  // obuf[w][q][36 slots]: in-loop = per-wave P buffer (rows 16w..16w+15);
  // post-loop = two-phase O^T merge buffer (32 d-slots + 4 pad per q-row).
  __shared__ __align__(16) float obuf[4 * 64 * 36];  // 36864 B
  __shared__ __align__(16) float scratch[512];       // bias in-loop / m,l post-loop

  const int qt = blockIdx.x, bh = blockIdx.y;
  const int b = bh >> 4, h = bh & 15;
  const int q0 = qt * 64;
  const int tid = threadIdx.x, w = tid >> 6, lane = tid & 63;
  const int g = lane >> 4, c = lane & 15;

  const float* btab = biasTab + h * 4095 + 2047;
  for (int i = tid; i < 441; i += 256) scratch[i] = btab[i - 220];
  const float cPos = btab[200], cNeg = btab[-200];  // saturated buckets (|rel|>=91)
  __syncthreads();

  // Q B-frags for all 64 q-rows of the block (resident whole kernel)
  bf16x8 qf0[4], qf1[4];
  const unsigned short* qbase = qb + ((long)(b * NN + q0)) * MODEL + h * 64;
#pragma unroll
  for (int nt = 0; nt < 4; ++nt) {
    const unsigned short* r = qbase + (16 * nt + c) * MODEL + 8 * g;
    qf0[nt] = *reinterpret_cast<const bf16x8*>(r);
    qf1[nt] = *reinterpret_cast<const bf16x8*>(r + 32);
  }

  const unsigned short* kbase = kb + ((long)b * NN) * MODEL + h * 64;
  const unsigned short* vbase = vtb + ((long)bh * 64) * NN;

  f32x4 o[4][4];
  float m_i[4], l_i[4];
#pragma unroll
  for (int nt = 0; nt < 4; ++nt) {
    m_i[nt] = -1e30f; l_i[nt] = 0.f;
#pragma unroll
    for (int mt = 0; mt < 4; ++mt) o[mt][nt] = f32x4{0.f, 0.f, 0.f, 0.f};
  }

  unsigned int* Pb = reinterpret_cast<unsigned int*>(obuf);
  const int ProwW = (w * 16 + c) * 36 + 2 * g;  // b64 write: slot 8mt+2g (+t)
  const int ProwR = (w * 16 + c) * 36 + 4 * g;  // b128 read base (16B aligned)

  for (int it = 0; it < 8; ++it) {
    const int kt = w + 4 * it;  // this wave's private key-tile
    bf16x8 kf0[4], kf1[4];
    const unsigned short* krow = kbase + (long)(kt * 64) * MODEL;
#pragma unroll
    for (int mt = 0; mt < 4; ++mt) {
      const unsigned short* r = krow + (16 * mt + c) * MODEL + 8 * g;
      kf0[mt] = *reinterpret_cast<const bf16x8*>(r);
      kf1[mt] = *reinterpret_cast<const bf16x8*>(r + 32);
    }
    // S^T = K * Q^T : lane (g,c) reg rr = S[qrow=16nt+c][key=16mt+4g+rr]
    f32x4 s[4][4];
#pragma unroll
    for (int mt = 0; mt < 4; ++mt)
#pragma unroll
      for (int nt = 0; nt < 4; ++nt) {
        s[mt][nt] = mfma16(kf0[mt], qf0[nt], f32x4{0.f, 0.f, 0.f, 0.f});
        s[mt][nt] = mfma16(kf1[mt], qf1[nt], s[mt][nt]);
      }
    // issue V loads now; latency hidden by softmax VALU
    bf16x8 vf0[4], vf1[4];
    const unsigned short* vrow = vbase + kt * 64;
#pragma unroll
    for (int mt = 0; mt < 4; ++mt) {
      const unsigned short* r = vrow + (long)(16 * mt + c) * NN + 8 * g;
      vf0[mt] = *reinterpret_cast<const bf16x8*>(r);
      vf1[mt] = *reinterpret_cast<const bf16x8*>(r + 32);
    }
    // logits (log2-domain): lg = s*CSC + bias2[rel]
    const int lo = kt * 64 - q0 - 63, hi = kt * 64 + 63 - q0;
    if (lo >= 91 || hi <= -91) {  // whole tile saturated: sgpr constant
      const float cb = (lo >= 91) ? cPos : cNeg;
#pragma unroll
      for (int mt = 0; mt < 4; ++mt)
#pragma unroll
        for (int nt = 0; nt < 4; ++nt)
#pragma unroll
          for (int rr = 0; rr < 4; ++rr)
            s[mt][nt][rr] = s[mt][nt][rr] * CSC + cb;
    } else {
      const int base = kt * 64 + 4 * g - q0 - c + 220;
#pragma unroll
      for (int mt = 0; mt < 4; ++mt)
#pragma unroll
        for (int nt = 0; nt < 4; ++nt) {
          const int idx = base + 16 * mt - 16 * nt;
#pragma unroll
          for (int rr = 0; rr < 4; ++rr)  // lanes w/ equal 4g-c broadcast
            s[mt][nt][rr] = s[mt][nt][rr] * CSC + scratch[idx + rr];
        }
    }
#pragma unroll
    for (int nt = 0; nt < 4; ++nt) {
      // all 64 keys of qrow=16nt+c live in lanes {c,c+16,c+32,c+48}
      float mx = s[0][nt][0];
#pragma unroll
      for (int mt = 0; mt < 4; ++mt)
#pragma unroll
        for (int rr = 0; rr < 4; ++rr) mx = fmaxf(mx, s[mt][nt][rr]);
      mx = fmaxf(mx, __shfl_xor(mx, 16));
      mx = fmaxf(mx, __shfl_xor(mx, 32));
      const float mn = fmaxf(m_i[nt], mx);
      const float al = fast_exp2(m_i[nt] - mn);
      m_i[nt] = mn;
      float sum = 0.f;
      unsigned int pk[4][2];
#pragma unroll
      for (int mt = 0; mt < 4; ++mt)
#pragma unroll
        for (int t = 0; t < 2; ++t) {
          const float p0 = fast_exp2(s[mt][nt][2 * t] - mn);
          const float p1 = fast_exp2(s[mt][nt][2 * t + 1] - mn);
          sum += p0 + p1;
          pk[mt][t] = pack_bf2(p0, p1);  // keys (16mt+4g+2t, +1)
        }
      sum += __shfl_xor(sum, 16);
      sum += __shfl_xor(sum, 32);
      l_i[nt] = l_i[nt] * al + sum;
#pragma unroll
      for (int mt = 0; mt < 4; ++mt) {
        o[mt][nt][0] *= al; o[mt][nt][1] *= al;
        o[mt][nt][2] *= al; o[mt][nt][3] *= al;
      }
      // P: C-layout -> b64 writes (even+odd banks, 4 instrs) -> B-frags
#pragma unroll
      for (int mt = 0; mt < 4; ++mt)
        *reinterpret_cast<uint2*>(&Pb[ProwW + 8 * mt]) = uint2{pk[mt][0], pk[mt][1]};
      const bf16x8 pb0 = *reinterpret_cast<const bf16x8*>(&Pb[ProwR]);
      const bf16x8 pb1 = *reinterpret_cast<const bf16x8*>(&Pb[ProwR + 16]);
#pragma unroll
      for (int mt = 0; mt < 4; ++mt) {
        o[mt][nt] = mfma16(vf0[mt], pb0, o[mt][nt]);  // O^T[d][qrow]
        o[mt][nt] = mfma16(vf1[mt], pb1, o[mt][nt]);
      }
    }
  }

  // ---- two-phase merge: phase A = d[0,32), phase B = d[32,64) ----
  __syncthreads();  // all waves done with Pb region & bias scratch
  float* ml = scratch;
  if (g == 0) {
#pragma unroll
    for (int nt = 0; nt < 4; ++nt) {
      ml[(w * 64 + 16 * nt + c) * 2] = m_i[nt];
      ml[(w * 64 + 16 * nt + c) * 2 + 1] = l_i[nt];
    }
  }
  // phase A writes (mt = 0,1 -> slots 0..31)
#pragma unroll
  for (int mt = 0; mt < 2; ++mt)
#pragma unroll
    for (int nt = 0; nt < 4; ++nt)
      *reinterpret_cast<f32x4*>(
          &obuf[(w * 64 + 16 * nt + c) * 36 + 16 * mt + 4 * g]) = o[mt][nt];
  __syncthreads();

  const int qr = 16 * w + c;  // owner wave w: q-rows 16w..16w+15; dims 8g+j
  float mu[4], lu[4];
#pragma unroll
  for (int u = 0; u < 4; ++u) {
    mu[u] = ml[(u * 64 + qr) * 2];
    lu[u] = ml[(u * 64 + qr) * 2 + 1];
  }
  float M = fmaxf(fmaxf(mu[0], mu[1]), fmaxf(mu[2], mu[3]));
  float L = 0.f, fu[4];
#pragma unroll
  for (int u = 0; u < 4; ++u) {
    fu[u] = fast_exp2(mu[u] - M);
    L += fu[u] * lu[u];
  }
  const float inv = 1.f / L;

  float acc[16];
#pragma unroll
  for (int j = 0; j < 16; ++j) acc[j] = 0.f;
#pragma unroll
  for (int u = 0; u < 4; ++u) {
    const float* src = obuf + (u * 64 + qr) * 36;
    f32x4 r0 = *reinterpret_cast<const f32x4*>(&src[8 * g]);
    f32x4 r1 = *reinterpret_cast<const f32x4*>(&src[8 * g + 4]);
#pragma unroll
    for (int j = 0; j < 4; ++j) {
      acc[j] += fu[u] * r0[j];
      acc[4 + j] += fu[u] * r1[j];
    }
  }
  __syncthreads();  // phase A reads done before phase B overwrites

  // phase B writes (mt = 2,3 -> slots 0..31)
#pragma unroll
  for (int mt = 2; mt < 4; ++mt)
#pragma unroll
    for (int nt = 0; nt < 4; ++nt)
      *reinterpret_cast<f32x4*>(
          &obuf[(w * 64 + 16 * nt + c) * 36 + 16 * (mt - 2) + 4 * g]) = o[mt][nt];
  __syncthreads();
#pragma unroll
  for (int u = 0; u < 4; ++u) {
    const float* src = obuf + (u * 64 + qr) * 36;
    f32x4 r0 = *reinterpret_cast<const f32x4*>(&src[8 * g]);
    f32x4 r1 = *reinterpret_cast<const f32x4*>(&src[8 * g + 4]);
#pragma unroll
    for (int j = 0; j < 4; ++j) {
      acc[8 + j] += fu[u] * r0[j];
      acc[12 + j] += fu[u] * r1[j];
    }
  }

  unsigned int od[8];
#pragma unroll
  for (int t = 0; t < 8; ++t) od[t] = pack_bf2(acc[2 * t] * inv, acc[2 * t + 1] * inv);
  unsigned short* orow = attn + ((long)(b * NN + q0 + qr)) * MODEL + h * 64;
  *reinterpret_cast<uint4*>(orow + 8 * g) = uint4{od[0], od[1], od[2], od[3]};
  *reinterpret_cast<uint4*>(orow + 32 + 8 * g) = uint4{od[4], od[5], od[6], od[7]};
}

// out[i][j] = sum_k attn[i][k] * w[j][k] + b[j]; tile 128(M)x64(N), grid 32x16
__global__ void proj_gemm_kernel(const unsigned short* __restrict__ A,
                                 const unsigned short* __restrict__ Bw,
                                 const float* __restrict__ bias,
                                 float* __restrict__ out) {
  __shared__ __align__(16) unsigned short At[128 * 32];
  __shared__ __align__(16) unsigned short Bt[64 * 32];
  int bm0 = blockIdx.x * 128, bn0 = blockIdx.y * 64;
  int tid = threadIdx.x, w = tid >> 6, lane = tid & 63;
  int g = lane >> 4, c = lane & 15;
  int m0 = (w & 1) * 64, n0 = (w >> 1) * 32;

  f32x4 zero = {0.f, 0.f, 0.f, 0.f};
  f32x4 acc[4][2];
#pragma unroll
  for (int mi = 0; mi < 4; ++mi)
#pragma unroll
    for (int nj = 0; nj < 2; ++nj) acc[mi][nj] = zero;

  int rl4 = lane >> 2, p4 = lane & 3;
  for (int kt = 0; kt < 32; ++kt) {
    __syncthreads();
#pragma unroll
    for (int t = 0; t < 2; ++t) {
      int row = w * 32 + t * 16 + rl4;
      int lc = p4 ^ (rl4 & 3);
      async_copy16(&At[(w * 32 + t * 16) * 32],
                   A + (long)(bm0 + row) * 1024 + kt * 32 + lc * 8);
    }
    {
      int row = w * 16 + rl4;
      int lc = p4 ^ (rl4 & 3);
      async_copy16(&Bt[(w * 16) * 32],
                   Bw + (long)(bn0 + row) * 1024 + kt * 32 + lc * 8);
    }
    __syncthreads();

    bf16x8 af[4], bfr[2];
#pragma unroll
    for (int mi = 0; mi < 4; ++mi) {
      int row = m0 + mi * 16 + c;
      af[mi] = *reinterpret_cast<const bf16x8*>(&At[row * 32 + (g ^ (row & 3)) * 8]);
    }
#pragma unroll
    for (int nj = 0; nj < 2; ++nj) {
      int row = n0 + nj * 16 + c;
      bfr[nj] = *reinterpret_cast<const bf16x8*>(&Bt[row * 32 + (g ^ (row & 3)) * 8]);
    }
#pragma unroll
    for (int mi = 0; mi < 4; ++mi)
#pragma unroll
      for (int nj = 0; nj < 2; ++nj)
        acc[mi][nj] = mfma16(af[mi], bfr[nj], acc[mi][nj]);
  }

#pragma unroll
  for (int mi = 0; mi < 4; ++mi)
#pragma unroll
    for (int nj = 0; nj < 2; ++nj)
#pragma unroll
      for (int r = 0; r < 4; ++r) {
        int row = bm0 + m0 + mi * 16 + 4 * g + r;
        int col = bn0 + n0 + nj * 16 + c;
        out[(long)row * 1024 + col] = acc[mi][nj][r] + bias[col];
      }
}

extern "C" void kernel_launch(void* const* d_in, const int* in_sizes, int n_in,
                              void* d_out, int out_size, void* d_ws, size_t ws_size,
                              hipStream_t stream) {
  const float* q = (const float*)d_in[0];
  const float* k = (const float*)d_in[1];
  const float* v = (const float*)d_in[2];
  const float* rel_emb = (const float*)d_in[3];
  const float* w_out = (const float*)d_in[4];
  const float* b_out = (const float*)d_in[5];
  float* out = (float*)d_out;

  char* ws = (char*)d_ws;
  unsigned short* qb   = (unsigned short*)(ws);
  unsigned short* kb   = (unsigned short*)(ws + (8u << 20));
  unsigned short* vt   = (unsigned short*)(ws + (16u << 20));
  unsigned short* attn = (unsigned short*)(ws + (24u << 20));
  unsigned short* wb   = (unsigned short*)(ws + (32u << 20));
  float* biasTab       = (float*)(ws + (34u << 20));

  hipLaunchKernelGGL(cvt3_kernel, dim3(9216), dim3(256), 0, stream,
                     q, k, w_out, qb, kb, wb);
  hipLaunchKernelGGL(transpose_v_kernel, dim3(NN / 64, BB * HH), dim3(256), 0, stream,
                     v, vt);
  hipLaunchKernelGGL(bias_table_kernel, dim3(16), dim3(256), 0, stream,
                     rel_emb, biasTab);
  hipLaunchKernelGGL(flash3, dim3(NN / 64, BB * HH), dim3(256), 0, stream,
                     qb, kb, vt, biasTab, attn);
  hipLaunchKernelGGL(proj_gemm_kernel, dim3(32, 16), dim3(256), 0, stream,
                     attn, wb, b_out, out);
}

// Round 4
// 307.845 us; speedup vs baseline: 1.7178x; 1.7178x over previous
//
#include <hip/hip_runtime.h>

#define BB 2
#define NN 2048
#define HH 16
#define MODEL 1024
#define CSC 0.18033688011112042f  // 0.125 * log2(e)

typedef short bf16x8 __attribute__((ext_vector_type(8)));
typedef float f32x4 __attribute__((ext_vector_type(4)));

__device__ __forceinline__ unsigned short f2bf(float x) {
  unsigned int u = __builtin_bit_cast(unsigned int, x);
  u += 0x7fffu + ((u >> 16) & 1u);
  return (unsigned short)(u >> 16);
}

__device__ __forceinline__ unsigned int pack_bf2(float a, float b) {
  unsigned int ua = __builtin_bit_cast(unsigned int, a) + 0x8000u;
  unsigned int ub = __builtin_bit_cast(unsigned int, b) + 0x8000u;
  return __builtin_amdgcn_perm(ub, ua, 0x07060302u);  // lo16=bf(a), hi16=bf(b)
}

__device__ __forceinline__ float fast_exp2(float x) {
#if __has_builtin(__builtin_amdgcn_exp2f)
  return __builtin_amdgcn_exp2f(x);
#else
  return exp2f(x);
#endif
}

__device__ __forceinline__ f32x4 mfma16(bf16x8 a, bf16x8 b, f32x4 c) {
  return __builtin_amdgcn_mfma_f32_16x16x32_bf16(a, b, c, 0, 0, 0);
}

__device__ __forceinline__ void async_copy16(void* lds_base, const void* g) {
  __builtin_amdgcn_global_load_lds(
      (const __attribute__((address_space(1))) void*)g,
      (__attribute__((address_space(3))) void*)lds_base, 16, 0, 0);
}

// fused bf16 conversion of q, k, w_out
__global__ void cvt3_kernel(const float* __restrict__ q, const float* __restrict__ k,
                            const float* __restrict__ w, unsigned short* __restrict__ qb,
                            unsigned short* __restrict__ kb, unsigned short* __restrict__ wb) {
  const int NQ = BB * NN * MODEL / 4;  // 1048576 float4s
  const int NW = MODEL * MODEL / 4;    // 262144
  int i = blockIdx.x * 256 + threadIdx.x;
  const float* src;
  unsigned short* dst;
  int j = i;
  if (i < NQ) {
    src = q; dst = qb;
  } else if (i < 2 * NQ) {
    src = k; dst = kb; j = i - NQ;
  } else if (i < 2 * NQ + NW) {
    src = w; dst = wb; j = i - 2 * NQ;
  } else {
    return;
  }
  float4 f = reinterpret_cast<const float4*>(src)[j];
  ushort4 u;
  u.x = f2bf(f.x); u.y = f2bf(f.y); u.z = f2bf(f.z); u.w = f2bf(f.w);
  reinterpret_cast<ushort4*>(dst)[j] = u;
}

// vt[b][h][d][n] = bf16(v[b][n][h*64+d])
__global__ void transpose_v_kernel(const float* __restrict__ v,
                                   unsigned short* __restrict__ vt) {
  __shared__ unsigned short tile[64][65];
  int n0 = blockIdx.x * 64;
  int bh = blockIdx.y;
  int b = bh >> 4, h = bh & 15;
  int c = threadIdx.x & 63;
  int r = threadIdx.x >> 6;
#pragma unroll
  for (int i = 0; i < 16; ++i) {
    int nl = r * 16 + i;
    tile[c][nl] = f2bf(v[((long)(b * NN + n0 + nl)) * MODEL + h * 64 + c]);
  }
  __syncthreads();
#pragma unroll
  for (int i = 0; i < 16; ++i) {
    int d = r * 16 + i;
    vt[((long)(bh * 64 + d)) * NN + n0 + c] = tile[d][c];
  }
}

// biasTab[h][rel+2047] = bias(rel) * 0.125 * log2(e)  (log2-domain, pre-scaled)
__global__ void bias_table_kernel(const float* __restrict__ rel_emb,
                                  float* __restrict__ biasTab) {
  int idx = blockIdx.x * 256 + threadIdx.x;
  if (idx >= 4095) return;
  int rel = idx - 2047;
  int nn = rel < 0 ? -rel : rel;
  int bucket;
  if (nn < 8) {
    bucket = nn;
  } else {
    float val = logf((float)nn * 0.125f) / logf(16.0f) * 8.0f;
    int vl = 8 + (int)val;
    if (vl > 15) vl = 15;
    bucket = vl;
  }
  if (rel >= 0) bucket += 16;
#pragma unroll
  for (int h = 0; h < 16; ++h)
    biasTab[h * 4095 + idx] = rel_emb[bucket * 16 + h] * CSC;
}

// Flash v4: kt-split waves, S^T, nt-outer softmax (s[4] only), Q from LDS,
// streamed V in PV phase. Reg demand ~165 -> 3 waves/SIMD without spill.
__global__ __launch_bounds__(256, 3) void flash4(
    const unsigned short* __restrict__ qb, const unsigned short* __restrict__ kb,
    const unsigned short* __restrict__ vtb, const float* __restrict__ biasTab,
    unsigned short* __restrict__ attn) {
  __shared__ __align__(16) float obuf[4 * 64 * 36];      // P in-loop / O merge post
  __shared__ __align__(16) float scratch[512];           // bias in-loop / m,l post
  __shared__ __align__(16) unsigned short Qs[64 * 72];   // Q tile, pad 64->72

  const int qt = blockIdx.x, bh = blockIdx.y;
  const int b = bh >> 4, h = bh & 15;
  const int q0 = qt * 64;
  const int tid = threadIdx.x, w = tid >> 6, lane = tid & 63;
  const int g = lane >> 4, c = lane & 15;

  const float* btab = biasTab + h * 4095 + 2047;
  for (int i = tid; i < 441; i += 256) scratch[i] = btab[i - 220];
  const float cPos = btab[200], cNeg = btab[-200];  // saturated buckets (|rel|>=91)

  // stage Q tile: 64 rows x 128B (256 thr x 2 x 16B)
  {
    const int row = tid >> 2, ch = tid & 3;
    const unsigned short* qg = qb + ((long)(b * NN + q0 + row)) * MODEL + h * 64;
    *reinterpret_cast<uint4*>(&Qs[row * 72 + ch * 8]) =
        *reinterpret_cast<const uint4*>(qg + ch * 8);
    *reinterpret_cast<uint4*>(&Qs[row * 72 + 32 + ch * 8]) =
        *reinterpret_cast<const uint4*>(qg + 32 + ch * 8);
  }
  __syncthreads();

  const unsigned short* kbase = kb + ((long)b * NN) * MODEL + h * 64;
  const unsigned short* vbase = vtb + ((long)bh * 64) * NN;

  f32x4 o[4][4];
  float m_i[4], l_i[4];
#pragma unroll
  for (int nt = 0; nt < 4; ++nt) {
    m_i[nt] = -1e30f; l_i[nt] = 0.f;
#pragma unroll
    for (int mt = 0; mt < 4; ++mt) o[mt][nt] = f32x4{0.f, 0.f, 0.f, 0.f};
  }

  unsigned int* Pb = reinterpret_cast<unsigned int*>(obuf);
  const int ProwW = (w * 16 + c) * 36 + 2 * g;  // b64 write: slot 8mt+2g(+t)
  const int ProwR = (w * 16 + c) * 36 + 4 * g;  // b128 read base

  for (int it = 0; it < 8; ++it) {
    const int kt = w + 4 * it;  // this wave's private key-tile
    bf16x8 kf0[4], kf1[4];
    const unsigned short* krow = kbase + (long)(kt * 64) * MODEL;
#pragma unroll
    for (int mt = 0; mt < 4; ++mt) {
      const unsigned short* r = krow + (16 * mt + c) * MODEL + 8 * g;
      kf0[mt] = *reinterpret_cast<const bf16x8*>(r);
      kf1[mt] = *reinterpret_cast<const bf16x8*>(r + 32);
    }
    const int lo = kt * 64 - q0 - 63, hi = kt * 64 + 63 - q0;
    const bool sat = (lo >= 91 || hi <= -91);
    const float cb = (lo >= 91) ? cPos : cNeg;

    bf16x8 pb0a[4], pb1a[4];
#pragma unroll
    for (int nt = 0; nt < 4; ++nt) {
      const bf16x8 qf0 = *reinterpret_cast<const bf16x8*>(&Qs[(16 * nt + c) * 72 + 8 * g]);
      const bf16x8 qf1 = *reinterpret_cast<const bf16x8*>(&Qs[(16 * nt + c) * 72 + 32 + 8 * g]);
      // S^T column group nt: lane (g,c) holds keys 16mt+4g+rr for qrow 16nt+c
      f32x4 s[4];
#pragma unroll
      for (int mt = 0; mt < 4; ++mt) {
        s[mt] = mfma16(kf0[mt], qf0, f32x4{0.f, 0.f, 0.f, 0.f});
        s[mt] = mfma16(kf1[mt], qf1, s[mt]);
      }
      // logits (log2-domain)
      if (sat) {
#pragma unroll
        for (int mt = 0; mt < 4; ++mt)
#pragma unroll
          for (int rr = 0; rr < 4; ++rr) s[mt][rr] = s[mt][rr] * CSC + cb;
      } else {
        const int base = kt * 64 + 4 * g - q0 - c + 220 - 16 * nt;
#pragma unroll
        for (int mt = 0; mt < 4; ++mt)
#pragma unroll
          for (int rr = 0; rr < 4; ++rr)
            s[mt][rr] = s[mt][rr] * CSC + scratch[base + 16 * mt + rr];
      }
      // online softmax for the 16 rows (row data in lanes {c,c+16,c+32,c+48})
      float mx = s[0][0];
#pragma unroll
      for (int mt = 0; mt < 4; ++mt)
#pragma unroll
        for (int rr = 0; rr < 4; ++rr) mx = fmaxf(mx, s[mt][rr]);
      mx = fmaxf(mx, __shfl_xor(mx, 16));
      mx = fmaxf(mx, __shfl_xor(mx, 32));
      const float mn = fmaxf(m_i[nt], mx);
      const float al = fast_exp2(m_i[nt] - mn);
      m_i[nt] = mn;
      float sum = 0.f;
      unsigned int pk[4][2];
#pragma unroll
      for (int mt = 0; mt < 4; ++mt)
#pragma unroll
        for (int t = 0; t < 2; ++t) {
          const float p0 = fast_exp2(s[mt][2 * t] - mn);
          const float p1 = fast_exp2(s[mt][2 * t + 1] - mn);
          sum += p0 + p1;
          pk[mt][t] = pack_bf2(p0, p1);
        }
      sum += __shfl_xor(sum, 16);
      sum += __shfl_xor(sum, 32);
      l_i[nt] = l_i[nt] * al + sum;
#pragma unroll
      for (int mt = 0; mt < 4; ++mt) {
        o[mt][nt][0] *= al; o[mt][nt][1] *= al;
        o[mt][nt][2] *= al; o[mt][nt][3] *= al;
      }
      // P: C-layout -> b64 LDS writes -> B-frags (wave-private rows, no barrier)
#pragma unroll
      for (int mt = 0; mt < 4; ++mt)
        *reinterpret_cast<uint2*>(&Pb[ProwW + 8 * mt]) = uint2{pk[mt][0], pk[mt][1]};
      pb0a[nt] = *reinterpret_cast<const bf16x8*>(&Pb[ProwR]);
      pb1a[nt] = *reinterpret_cast<const bf16x8*>(&Pb[ProwR + 16]);
    }

    // PV phase: stream V fragments (one mt ahead), o^T[d][q] accumulate
    const unsigned short* vrow = vbase + kt * 64;
    bf16x8 cv0 = *reinterpret_cast<const bf16x8*>(vrow + (long)c * NN + 8 * g);
    bf16x8 cv1 = *reinterpret_cast<const bf16x8*>(vrow + (long)c * NN + 8 * g + 32);
#pragma unroll
    for (int mt = 0; mt < 4; ++mt) {
      bf16x8 nv0, nv1;
      if (mt < 3) {
        const unsigned short* r = vrow + (long)(16 * (mt + 1) + c) * NN + 8 * g;
        nv0 = *reinterpret_cast<const bf16x8*>(r);
        nv1 = *reinterpret_cast<const bf16x8*>(r + 32);
      }
#pragma unroll
      for (int nt = 0; nt < 4; ++nt) o[mt][nt] = mfma16(cv0, pb0a[nt], o[mt][nt]);
#pragma unroll
      for (int nt = 0; nt < 4; ++nt) o[mt][nt] = mfma16(cv1, pb1a[nt], o[mt][nt]);
      cv0 = nv0; cv1 = nv1;
    }
  }

  // ---- two-phase merge: phase A = d[0,32), phase B = d[32,64) ----
  __syncthreads();  // all waves done with Pb region & bias scratch
  float* ml = scratch;
  if (g == 0) {
#pragma unroll
    for (int nt = 0; nt < 4; ++nt) {
      ml[(w * 64 + 16 * nt + c) * 2] = m_i[nt];
      ml[(w * 64 + 16 * nt + c) * 2 + 1] = l_i[nt];
    }
  }
#pragma unroll
  for (int mt = 0; mt < 2; ++mt)
#pragma unroll
    for (int nt = 0; nt < 4; ++nt)
      *reinterpret_cast<f32x4*>(
          &obuf[(w * 64 + 16 * nt + c) * 36 + 16 * mt + 4 * g]) = o[mt][nt];
  __syncthreads();

  const int qr = 16 * w + c;  // owner wave w: q-rows 16w..16w+15; dims 8g+j
  float mu[4], lu[4];
#pragma unroll
  for (int u = 0; u < 4; ++u) {
    mu[u] = ml[(u * 64 + qr) * 2];
    lu[u] = ml[(u * 64 + qr) * 2 + 1];
  }
  float M = fmaxf(fmaxf(mu[0], mu[1]), fmaxf(mu[2], mu[3]));
  float L = 0.f, fu[4];
#pragma unroll
  for (int u = 0; u < 4; ++u) {
    fu[u] = fast_exp2(mu[u] - M);
    L += fu[u] * lu[u];
  }
  const float inv = 1.f / L;

  float acc[16];
#pragma unroll
  for (int j = 0; j < 16; ++j) acc[j] = 0.f;
#pragma unroll
  for (int u = 0; u < 4; ++u) {
    const float* src = obuf + (u * 64 + qr) * 36;
    f32x4 r0 = *reinterpret_cast<const f32x4*>(&src[8 * g]);
    f32x4 r1 = *reinterpret_cast<const f32x4*>(&src[8 * g + 4]);
#pragma unroll
    for (int j = 0; j < 4; ++j) {
      acc[j] += fu[u] * r0[j];
      acc[4 + j] += fu[u] * r1[j];
    }
  }
  __syncthreads();  // phase A reads done before phase B overwrites

#pragma unroll
  for (int mt = 2; mt < 4; ++mt)
#pragma unroll
    for (int nt = 0; nt < 4; ++nt)
      *reinterpret_cast<f32x4*>(
          &obuf[(w * 64 + 16 * nt + c) * 36 + 16 * (mt - 2) + 4 * g]) = o[mt][nt];
  __syncthreads();
#pragma unroll
  for (int u = 0; u < 4; ++u) {
    const float* src = obuf + (u * 64 + qr) * 36;
    f32x4 r0 = *reinterpret_cast<const f32x4*>(&src[8 * g]);
    f32x4 r1 = *reinterpret_cast<const f32x4*>(&src[8 * g + 4]);
#pragma unroll
    for (int j = 0; j < 4; ++j) {
      acc[8 + j] += fu[u] * r0[j];
      acc[12 + j] += fu[u] * r1[j];
    }
  }

  unsigned int od[8];
#pragma unroll
  for (int t = 0; t < 8; ++t) od[t] = pack_bf2(acc[2 * t] * inv, acc[2 * t + 1] * inv);
  unsigned short* orow = attn + ((long)(b * NN + q0 + qr)) * MODEL + h * 64;
  *reinterpret_cast<uint4*>(orow + 8 * g) = uint4{od[0], od[1], od[2], od[3]};
  *reinterpret_cast<uint4*>(orow + 32 + 8 * g) = uint4{od[4], od[5], od[6], od[7]};
}

// out[i][j] = sum_k attn[i][k] * w[j][k] + b[j]; tile 128(M)x64(N), grid 32x16
__global__ void proj_gemm_kernel(const unsigned short* __restrict__ A,
                                 const unsigned short* __restrict__ Bw,
                                 const float* __restrict__ bias,
                                 float* __restrict__ out) {
  __shared__ __align__(16) unsigned short At[128 * 32];
  __shared__ __align__(16) unsigned short Bt[64 * 32];
  int bm0 = blockIdx.x * 128, bn0 = blockIdx.y * 64;
  int tid = threadIdx.x, w = tid >> 6, lane = tid & 63;
  int g = lane >> 4, c = lane & 15;
  int m0 = (w & 1) * 64, n0 = (w >> 1) * 32;

  f32x4 zero = {0.f, 0.f, 0.f, 0.f};
  f32x4 acc[4][2];
#pragma unroll
  for (int mi = 0; mi < 4; ++mi)
#pragma unroll
    for (int nj = 0; nj < 2; ++nj) acc[mi][nj] = zero;

  int rl4 = lane >> 2, p4 = lane & 3;
  for (int kt = 0; kt < 32; ++kt) {
    __syncthreads();
#pragma unroll
    for (int t = 0; t < 2; ++t) {
      int row = w * 32 + t * 16 + rl4;
      int lc = p4 ^ (rl4 & 3);
      async_copy16(&At[(w * 32 + t * 16) * 32],
                   A + (long)(bm0 + row) * 1024 + kt * 32 + lc * 8);
    }
    {
      int row = w * 16 + rl4;
      int lc = p4 ^ (rl4 & 3);
      async_copy16(&Bt[(w * 16) * 32],
                   Bw + (long)(bn0 + row) * 1024 + kt * 32 + lc * 8);
    }
    __syncthreads();

    bf16x8 af[4], bfr[2];
#pragma unroll
    for (int mi = 0; mi < 4; ++mi) {
      int row = m0 + mi * 16 + c;
      af[mi] = *reinterpret_cast<const bf16x8*>(&At[row * 32 + (g ^ (row & 3)) * 8]);
    }
#pragma unroll
    for (int nj = 0; nj < 2; ++nj) {
      int row = n0 + nj * 16 + c;
      bfr[nj] = *reinterpret_cast<const bf16x8*>(&Bt[row * 32 + (g ^ (row & 3)) * 8]);
    }
#pragma unroll
    for (int mi = 0; mi < 4; ++mi)
#pragma unroll
      for (int nj = 0; nj < 2; ++nj)
        acc[mi][nj] = mfma16(af[mi], bfr[nj], acc[mi][nj]);
  }

#pragma unroll
  for (int mi = 0; mi < 4; ++mi)
#pragma unroll
    for (int nj = 0; nj < 2; ++nj)
#pragma unroll
      for (int r = 0; r < 4; ++r) {
        int row = bm0 + m0 + mi * 16 + 4 * g + r;
        int col = bn0 + n0 + nj * 16 + c;
        out[(long)row * 1024 + col] = acc[mi][nj][r] + bias[col];
      }
}

extern "C" void kernel_launch(void* const* d_in, const int* in_sizes, int n_in,
                              void* d_out, int out_size, void* d_ws, size_t ws_size,
                              hipStream_t stream) {
  const float* q = (const float*)d_in[0];
  const float* k = (const float*)d_in[1];
  const float* v = (const float*)d_in[2];
  const float* rel_emb = (const float*)d_in[3];
  const float* w_out = (const float*)d_in[4];
  const float* b_out = (const float*)d_in[5];
  float* out = (float*)d_out;

  char* ws = (char*)d_ws;
  unsigned short* qb   = (unsigned short*)(ws);
  unsigned short* kb   = (unsigned short*)(ws + (8u << 20));
  unsigned short* vt   = (unsigned short*)(ws + (16u << 20));
  unsigned short* attn = (unsigned short*)(ws + (24u << 20));
  unsigned short* wb   = (unsigned short*)(ws + (32u << 20));
  float* biasTab       = (float*)(ws + (34u << 20));

  hipLaunchKernelGGL(cvt3_kernel, dim3(9216), dim3(256), 0, stream,
                     q, k, w_out, qb, kb, wb);
  hipLaunchKernelGGL(transpose_v_kernel, dim3(NN / 64, BB * HH), dim3(256), 0, stream,
                     v, vt);
  hipLaunchKernelGGL(bias_table_kernel, dim3(16), dim3(256), 0, stream,
                     rel_emb, biasTab);
  hipLaunchKernelGGL(flash4, dim3(NN / 64, BB * HH), dim3(256), 0, stream,
                     qb, kb, vt, biasTab, attn);
  hipLaunchKernelGGL(proj_gemm_kernel, dim3(32, 16), dim3(256), 0, stream,
                     attn, wb, b_out, out);
}

// Round 5
// 235.643 us; speedup vs baseline: 2.2441x; 1.3064x over previous
//
#include <hip/hip_runtime.h>

#define BB 2
#define NN 2048
#define HH 16
#define MODEL 1024
#define CSC 0.18033688011112042f  // 0.125 * log2(e)

typedef short bf16x8 __attribute__((ext_vector_type(8)));
typedef float f32x4 __attribute__((ext_vector_type(4)));

__device__ __forceinline__ unsigned short f2bf(float x) {
  unsigned int u = __builtin_bit_cast(unsigned int, x);
  u += 0x7fffu + ((u >> 16) & 1u);
  return (unsigned short)(u >> 16);
}

__device__ __forceinline__ unsigned int pack_bf2(float a, float b) {
  unsigned int ua = __builtin_bit_cast(unsigned int, a) + 0x8000u;
  unsigned int ub = __builtin_bit_cast(unsigned int, b) + 0x8000u;
  return __builtin_amdgcn_perm(ub, ua, 0x07060302u);  // lo16=bf(a), hi16=bf(b)
}

__device__ __forceinline__ float fast_exp2(float x) {
#if __has_builtin(__builtin_amdgcn_exp2f)
  return __builtin_amdgcn_exp2f(x);
#else
  return exp2f(x);
#endif
}

__device__ __forceinline__ f32x4 mfma16(bf16x8 a, bf16x8 b, f32x4 c) {
  return __builtin_amdgcn_mfma_f32_16x16x32_bf16(a, b, c, 0, 0, 0);
}

__device__ __forceinline__ void async_copy16(void* lds_base, const void* g) {
  __builtin_amdgcn_global_load_lds(
      (const __attribute__((address_space(1))) void*)g,
      (__attribute__((address_space(3))) void*)lds_base, 16, 0, 0);
}

// One fused prep kernel: q/k/w bf16 cvt + V transpose + bias table.
// Section by blockIdx: [0,9216) cvt, [9216,10240) vtrans, [10240,10257) bias.
__global__ void prep_kernel(const float* __restrict__ q, const float* __restrict__ k,
                            const float* __restrict__ w, const float* __restrict__ v,
                            const float* __restrict__ rel_emb,
                            unsigned short* __restrict__ qb, unsigned short* __restrict__ kb,
                            unsigned short* __restrict__ wb, unsigned short* __restrict__ vt,
                            float* __restrict__ biasTab) {
  __shared__ unsigned short tile[64][65];
  const int NQ4 = BB * NN * MODEL / 4;  // 1048576
  const int blk = blockIdx.x;
  if (blk < 9216) {  // 9216*256 == 2*NQ4 + MODEL*MODEL/4 exactly
    int i = blk * 256 + threadIdx.x;
    const float* src;
    unsigned short* dst;
    int j = i;
    if (i < NQ4) {
      src = q; dst = qb;
    } else if (i < 2 * NQ4) {
      src = k; dst = kb; j = i - NQ4;
    } else {
      src = w; dst = wb; j = i - 2 * NQ4;
    }
    float4 f = reinterpret_cast<const float4*>(src)[j];
    ushort4 u;
    u.x = f2bf(f.x); u.y = f2bf(f.y); u.z = f2bf(f.z); u.w = f2bf(f.w);
    reinterpret_cast<ushort4*>(dst)[j] = u;
  } else if (blk < 10240) {  // vt[b][h][d][n] = bf16(v[b][n][h*64+d])
    const int blk2 = blk - 9216;
    const int n0 = (blk2 & 31) * 64;
    const int bh = blk2 >> 5;
    const int b = bh >> 4, h = bh & 15;
    const int c = threadIdx.x & 63;
    const int r = threadIdx.x >> 6;
#pragma unroll
    for (int i = 0; i < 16; ++i) {
      int nl = r * 16 + i;
      tile[c][nl] = f2bf(v[((long)(b * NN + n0 + nl)) * MODEL + h * 64 + c]);
    }
    __syncthreads();
#pragma unroll
    for (int i = 0; i < 16; ++i) {
      int d = r * 16 + i;
      vt[((long)(bh * 64 + d)) * NN + n0 + c] = tile[d][c];
    }
  } else {  // biasTab[h][rel+2047] = bias(rel)*CSC (log2-domain, pre-scaled)
    int idx = (blk - 10240) * 256 + threadIdx.x;
    if (idx >= 4095) return;
    int rel = idx - 2047;
    int nn = rel < 0 ? -rel : rel;
    int bucket;
    if (nn < 8) {
      bucket = nn;
    } else {
      float val = logf((float)nn * 0.125f) / logf(16.0f) * 8.0f;
      int vl = 8 + (int)val;
      if (vl > 15) vl = 15;
      bucket = vl;
    }
    if (rel >= 0) bucket += 16;
#pragma unroll
    for (int h = 0; h < 16; ++h)
      biasTab[h * 4095 + idx] = rel_emb[bucket * 16 + h] * CSC;
  }
}

// Flash v5: per-wave kt, S^T layout, nt-outer softmax (s[4] only), PV inside
// nt loop (pb transient), Q from LDS, b64 P-writes (conflict-free), explicit
// next-kt K prefetch, XCD-aware block swizzle. Target ~220 regs @ (256,2).
__global__ __launch_bounds__(256, 2) void flash5(
    const unsigned short* __restrict__ qb, const unsigned short* __restrict__ kb,
    const unsigned short* __restrict__ vtb, const float* __restrict__ biasTab,
    unsigned short* __restrict__ attn) {
  __shared__ __align__(16) float obuf[4 * 64 * 36];      // P in-loop / O merge post
  __shared__ __align__(16) float scratch[512];           // bias in-loop / m,l post
  __shared__ __align__(16) unsigned short Qs[64 * 72];   // Q tile, pad 64->72

  // XCD swizzle: dispatch round-robins blocks across 8 XCDs; group all 32
  // q-tiles of one bh onto one XCD so its K/V stay L2-resident (2MB/XCD).
  const int i = blockIdx.x;
  const int bh = (i & 7) * 4 + ((i >> 3) >> 5);
  const int qt = (i >> 3) & 31;
  const int b = bh >> 4, h = bh & 15;
  const int q0 = qt * 64;
  const int tid = threadIdx.x, w = tid >> 6, lane = tid & 63;
  const int g = lane >> 4, c = lane & 15;

  const float* btab = biasTab + h * 4095 + 2047;
  for (int j = tid; j < 441; j += 256) scratch[j] = btab[j - 220];
  const float cPos = btab[200], cNeg = btab[-200];  // saturated buckets (|rel|>=91)

  // stage Q tile: 64 rows x 128B (256 thr x 2 x 16B)
  {
    const int row = tid >> 2, ch = tid & 3;
    const unsigned short* qg = qb + ((long)(b * NN + q0 + row)) * MODEL + h * 64;
    *reinterpret_cast<uint4*>(&Qs[row * 72 + ch * 8]) =
        *reinterpret_cast<const uint4*>(qg + ch * 8);
    *reinterpret_cast<uint4*>(&Qs[row * 72 + 32 + ch * 8]) =
        *reinterpret_cast<const uint4*>(qg + 32 + ch * 8);
  }
  __syncthreads();

  const unsigned short* kbase = kb + ((long)b * NN) * MODEL + h * 64;
  const unsigned short* vbase = vtb + ((long)bh * 64) * NN;

  f32x4 o[4][4];
  float m_i[4], l_i[4];
#pragma unroll
  for (int nt = 0; nt < 4; ++nt) {
    m_i[nt] = -1e30f; l_i[nt] = 0.f;
#pragma unroll
    for (int mt = 0; mt < 4; ++mt) o[mt][nt] = f32x4{0.f, 0.f, 0.f, 0.f};
  }

  unsigned int* Pb = reinterpret_cast<unsigned int*>(obuf);
  const int ProwW = (w * 16 + c) * 36 + 2 * g;  // b64 write: slots 8mt+2g,+1
  const int ProwR = (w * 16 + c) * 36 + 4 * g;  // b128 read base

  // prologue: K fragments for it=0
  bf16x8 kf0[4], kf1[4];
  {
    const unsigned short* krow = kbase + (long)(w * 64) * MODEL;
#pragma unroll
    for (int mt = 0; mt < 4; ++mt) {
      const unsigned short* r = krow + (16 * mt + c) * MODEL + 8 * g;
      kf0[mt] = *reinterpret_cast<const bf16x8*>(r);
      kf1[mt] = *reinterpret_cast<const bf16x8*>(r + 32);
    }
  }

#pragma unroll 1
  for (int it = 0; it < 8; ++it) {
    const int kt = w + 4 * it;
    // V fragments for current kt (first use ~600 cyc later, after softmax)
    bf16x8 vf0[4], vf1[4];
    const unsigned short* vrow = vbase + kt * 64;
#pragma unroll
    for (int mt = 0; mt < 4; ++mt) {
      const unsigned short* r = vrow + (long)(16 * mt + c) * NN + 8 * g;
      vf0[mt] = *reinterpret_cast<const bf16x8*>(r);
      vf1[mt] = *reinterpret_cast<const bf16x8*>(r + 32);
    }
    // prefetch next iter's K (used ~full iter later)
    bf16x8 kn0[4], kn1[4];
    {
      const int ktn = (it < 7) ? kt + 4 : kt;
      const unsigned short* krow = kbase + (long)(ktn * 64) * MODEL;
#pragma unroll
      for (int mt = 0; mt < 4; ++mt) {
        const unsigned short* r = krow + (16 * mt + c) * MODEL + 8 * g;
        kn0[mt] = *reinterpret_cast<const bf16x8*>(r);
        kn1[mt] = *reinterpret_cast<const bf16x8*>(r + 32);
      }
    }
    const int lo = kt * 64 - q0 - 63, hi = kt * 64 + 63 - q0;
    const bool sat = (lo >= 91 || hi <= -91);
    const float cb = (lo >= 91) ? cPos : cNeg;

#pragma unroll
    for (int nt = 0; nt < 4; ++nt) {
      const bf16x8 qf0 = *reinterpret_cast<const bf16x8*>(&Qs[(16 * nt + c) * 72 + 8 * g]);
      const bf16x8 qf1 = *reinterpret_cast<const bf16x8*>(&Qs[(16 * nt + c) * 72 + 32 + 8 * g]);
      // S^T column group nt: lane (g,c) holds keys 16mt+4g+rr for qrow 16nt+c
      f32x4 s[4];
#pragma unroll
      for (int mt = 0; mt < 4; ++mt) {
        s[mt] = mfma16(kf0[mt], qf0, f32x4{0.f, 0.f, 0.f, 0.f});
        s[mt] = mfma16(kf1[mt], qf1, s[mt]);
      }
      if (sat) {
#pragma unroll
        for (int mt = 0; mt < 4; ++mt)
#pragma unroll
          for (int rr = 0; rr < 4; ++rr) s[mt][rr] = s[mt][rr] * CSC + cb;
      } else {
        const int base = kt * 64 + 4 * g - q0 - c + 220 - 16 * nt;
#pragma unroll
        for (int mt = 0; mt < 4; ++mt)
#pragma unroll
          for (int rr = 0; rr < 4; ++rr)
            s[mt][rr] = s[mt][rr] * CSC + scratch[base + 16 * mt + rr];
      }
      // online softmax for 16 q-rows (row data in lanes {c,c+16,c+32,c+48})
      float mx = s[0][0];
#pragma unroll
      for (int mt = 0; mt < 4; ++mt)
#pragma unroll
        for (int rr = 0; rr < 4; ++rr) mx = fmaxf(mx, s[mt][rr]);
      mx = fmaxf(mx, __shfl_xor(mx, 16));
      mx = fmaxf(mx, __shfl_xor(mx, 32));
      const float mn = fmaxf(m_i[nt], mx);
      const float al = fast_exp2(m_i[nt] - mn);
      m_i[nt] = mn;
      float sum = 0.f;
      unsigned int pk[4][2];
#pragma unroll
      for (int mt = 0; mt < 4; ++mt)
#pragma unroll
        for (int t = 0; t < 2; ++t) {
          const float p0 = fast_exp2(s[mt][2 * t] - mn);
          const float p1 = fast_exp2(s[mt][2 * t + 1] - mn);
          sum += p0 + p1;
          pk[mt][t] = pack_bf2(p0, p1);
        }
      sum += __shfl_xor(sum, 16);
      sum += __shfl_xor(sum, 32);
      l_i[nt] = l_i[nt] * al + sum;
#pragma unroll
      for (int mt = 0; mt < 4; ++mt) {
        o[mt][nt][0] *= al; o[mt][nt][1] *= al;
        o[mt][nt][2] *= al; o[mt][nt][3] *= al;
      }
      // P: C-layout -> b64 LDS writes (even+odd bank coverage) -> B-frags
#pragma unroll
      for (int mt = 0; mt < 4; ++mt)
        *reinterpret_cast<uint2*>(&Pb[ProwW + 8 * mt]) = uint2{pk[mt][0], pk[mt][1]};
      const bf16x8 pb0 = *reinterpret_cast<const bf16x8*>(&Pb[ProwR]);
      const bf16x8 pb1 = *reinterpret_cast<const bf16x8*>(&Pb[ProwR + 16]);
#pragma unroll
      for (int mt = 0; mt < 4; ++mt) {
        o[mt][nt] = mfma16(vf0[mt], pb0, o[mt][nt]);  // O^T[d][qrow]
        o[mt][nt] = mfma16(vf1[mt], pb1, o[mt][nt]);
      }
    }
    // rotate prefetched K
#pragma unroll
    for (int mt = 0; mt < 4; ++mt) { kf0[mt] = kn0[mt]; kf1[mt] = kn1[mt]; }
  }

  // ---- two-phase merge: phase A = d[0,32), phase B = d[32,64) ----
  __syncthreads();  // all waves done with Pb region & bias scratch
  float* ml = scratch;
  if (g == 0) {
#pragma unroll
    for (int nt = 0; nt < 4; ++nt) {
      ml[(w * 64 + 16 * nt + c) * 2] = m_i[nt];
      ml[(w * 64 + 16 * nt + c) * 2 + 1] = l_i[nt];
    }
  }
#pragma unroll
  for (int mt = 0; mt < 2; ++mt)
#pragma unroll
    for (int nt = 0; nt < 4; ++nt)
      *reinterpret_cast<f32x4*>(
          &obuf[(w * 64 + 16 * nt + c) * 36 + 16 * mt + 4 * g]) = o[mt][nt];
  __syncthreads();

  const int qr = 16 * w + c;  // owner wave w: q-rows 16w..16w+15; dims 8g+j
  float mu[4], lu[4];
#pragma unroll
  for (int u = 0; u < 4; ++u) {
    mu[u] = ml[(u * 64 + qr) * 2];
    lu[u] = ml[(u * 64 + qr) * 2 + 1];
  }
  float M = fmaxf(fmaxf(mu[0], mu[1]), fmaxf(mu[2], mu[3]));
  float L = 0.f, fu[4];
#pragma unroll
  for (int u = 0; u < 4; ++u) {
    fu[u] = fast_exp2(mu[u] - M);
    L += fu[u] * lu[u];
  }
  const float inv = 1.f / L;

  float acc[16];
#pragma unroll
  for (int j = 0; j < 16; ++j) acc[j] = 0.f;
#pragma unroll
  for (int u = 0; u < 4; ++u) {
    const float* src = obuf + (u * 64 + qr) * 36;
    f32x4 r0 = *reinterpret_cast<const f32x4*>(&src[8 * g]);
    f32x4 r1 = *reinterpret_cast<const f32x4*>(&src[8 * g + 4]);
#pragma unroll
    for (int j = 0; j < 4; ++j) {
      acc[j] += fu[u] * r0[j];
      acc[4 + j] += fu[u] * r1[j];
    }
  }
  __syncthreads();  // phase A reads done before phase B overwrites

#pragma unroll
  for (int mt = 2; mt < 4; ++mt)
#pragma unroll
    for (int nt = 0; nt < 4; ++nt)
      *reinterpret_cast<f32x4*>(
          &obuf[(w * 64 + 16 * nt + c) * 36 + 16 * (mt - 2) + 4 * g]) = o[mt][nt];
  __syncthreads();
#pragma unroll
  for (int u = 0; u < 4; ++u) {
    const float* src = obuf + (u * 64 + qr) * 36;
    f32x4 r0 = *reinterpret_cast<const f32x4*>(&src[8 * g]);
    f32x4 r1 = *reinterpret_cast<const f32x4*>(&src[8 * g + 4]);
#pragma unroll
    for (int j = 0; j < 4; ++j) {
      acc[8 + j] += fu[u] * r0[j];
      acc[12 + j] += fu[u] * r1[j];
    }
  }

  unsigned int od[8];
#pragma unroll
  for (int t = 0; t < 8; ++t) od[t] = pack_bf2(acc[2 * t] * inv, acc[2 * t + 1] * inv);
  unsigned short* orow = attn + ((long)(b * NN + q0 + qr)) * MODEL + h * 64;
  *reinterpret_cast<uint4*>(orow + 8 * g) = uint4{od[0], od[1], od[2], od[3]};
  *reinterpret_cast<uint4*>(orow + 32 + 8 * g) = uint4{od[4], od[5], od[6], od[7]};
}

// out[i][j] = sum_k attn[i][k] * w[j][k] + b[j]; tile 128(M)x64(N), grid 512
__global__ void proj_gemm_kernel(const unsigned short* __restrict__ A,
                                 const unsigned short* __restrict__ Bw,
                                 const float* __restrict__ bias,
                                 float* __restrict__ out) {
  __shared__ __align__(16) unsigned short At[128 * 32];
  __shared__ __align__(16) unsigned short Bt[64 * 32];
  int bm0 = blockIdx.x * 128, bn0 = blockIdx.y * 64;
  int tid = threadIdx.x, w = tid >> 6, lane = tid & 63;
  int g = lane >> 4, c = lane & 15;
  int m0 = (w & 1) * 64, n0 = (w >> 1) * 32;

  f32x4 zero = {0.f, 0.f, 0.f, 0.f};
  f32x4 acc[4][2];
#pragma unroll
  for (int mi = 0; mi < 4; ++mi)
#pragma unroll
    for (int nj = 0; nj < 2; ++nj) acc[mi][nj] = zero;

  int rl4 = lane >> 2, p4 = lane & 3;
  for (int kt = 0; kt < 32; ++kt) {
    __syncthreads();
#pragma unroll
    for (int t = 0; t < 2; ++t) {
      int row = w * 32 + t * 16 + rl4;
      int lc = p4 ^ (rl4 & 3);
      async_copy16(&At[(w * 32 + t * 16) * 32],
                   A + (long)(bm0 + row) * 1024 + kt * 32 + lc * 8);
    }
    {
      int row = w * 16 + rl4;
      int lc = p4 ^ (rl4 & 3);
      async_copy16(&Bt[(w * 16) * 32],
                   Bw + (long)(bn0 + row) * 1024 + kt * 32 + lc * 8);
    }
    __syncthreads();

    bf16x8 af[4], bfr[2];
#pragma unroll
    for (int mi = 0; mi < 4; ++mi) {
      int row = m0 + mi * 16 + c;
      af[mi] = *reinterpret_cast<const bf16x8*>(&At[row * 32 + (g ^ (row & 3)) * 8]);
    }
#pragma unroll
    for (int nj = 0; nj < 2; ++nj) {
      int row = n0 + nj * 16 + c;
      bfr[nj] = *reinterpret_cast<const bf16x8*>(&Bt[row * 32 + (g ^ (row & 3)) * 8]);
    }
#pragma unroll
    for (int mi = 0; mi < 4; ++mi)
#pragma unroll
      for (int nj = 0; nj < 2; ++nj)
        acc[mi][nj] = mfma16(af[mi], bfr[nj], acc[mi][nj]);
  }

#pragma unroll
  for (int mi = 0; mi < 4; ++mi)
#pragma unroll
    for (int nj = 0; nj < 2; ++nj)
#pragma unroll
      for (int r = 0; r < 4; ++r) {
        int row = bm0 + m0 + mi * 16 + 4 * g + r;
        int col = bn0 + n0 + nj * 16 + c;
        out[(long)row * 1024 + col] = acc[mi][nj][r] + bias[col];
      }
}

extern "C" void kernel_launch(void* const* d_in, const int* in_sizes, int n_in,
                              void* d_out, int out_size, void* d_ws, size_t ws_size,
                              hipStream_t stream) {
  const float* q = (const float*)d_in[0];
  const float* k = (const float*)d_in[1];
  const float* v = (const float*)d_in[2];
  const float* rel_emb = (const float*)d_in[3];
  const float* w_out = (const float*)d_in[4];
  const float* b_out = (const float*)d_in[5];
  float* out = (float*)d_out;

  char* ws = (char*)d_ws;
  unsigned short* qb   = (unsigned short*)(ws);
  unsigned short* kb   = (unsigned short*)(ws + (8u << 20));
  unsigned short* vt   = (unsigned short*)(ws + (16u << 20));
  unsigned short* attn = (unsigned short*)(ws + (24u << 20));
  unsigned short* wb   = (unsigned short*)(ws + (32u << 20));
  float* biasTab       = (float*)(ws + (34u << 20));

  hipLaunchKernelGGL(prep_kernel, dim3(10257), dim3(256), 0, stream,
                     q, k, w_out, v, rel_emb, qb, kb, wb, vt, biasTab);
  hipLaunchKernelGGL(flash5, dim3(1024), dim3(256), 0, stream,
                     qb, kb, vt, biasTab, attn);
  hipLaunchKernelGGL(proj_gemm_kernel, dim3(32, 16), dim3(256), 0, stream,
                     attn, wb, b_out, out);
}